// Round 3
// baseline (391.163 us; speedup 1.0000x reference)
//
#include <hip/hip_runtime.h>

// TopK_36653250904599: x [16,256,128,128] f32 -> l2-normalize over HW=16384,
// top-16 values [B,C,16] + (h,w) coords [B,C,16,2] (coords stored as floats;
// harness reads whole tuple buffer as float32).
//
// R3: kill the per-component ballot/leader-atomic/shfl chains (R2's filter
// cost ~1.3us/wave of LDS-latency, comparable to the 2.66us/block HBM budget
// -> BW stuck at ~2.3 TB/s). New filter: branchless 32-bit candidate mask
// per thread (pure VALU), ONE exec-masked LDS atomicAdd per thread with
// candidates (~18% of lanes) to reserve popc(mask) slots, then a predicated
// unrolled write loop. 512-thread blocks, 8 float4/thread -> ~50 VGPRs,
// __launch_bounds__(512,8) for 8 waves/SIMD latency hiding.
// Candidate order in s_cand is irrelevant: rank phase orders by (value,idx).

#define KSEL 16
#define HW   16384
#define WDIM 128
#define CAP  1024
#define T0   2.5f
#define NROWS 4096
#define NT   512
#define PER  8                      // float4 per thread
#define VALS_TOTAL (NROWS * KSEL)   // 65536 value floats, then coords

__global__ __launch_bounds__(NT, 8) void topk_rows(const float* __restrict__ x,
                                                   float* __restrict__ out) {
    const int row  = blockIdx.x;
    const int t    = threadIdx.x;
    const int lane = t & 63;

    __shared__ unsigned long long s_cand[CAP];
    __shared__ unsigned s_cnt;
    __shared__ float s_part[NT / 64];
    __shared__ float s_scale;

    const float4* rowp = (const float4*)(x + (size_t)row * HW);

    // ---- one unbroken batch of 8 independent 16B loads ----
    float4 buf[PER];
    #pragma unroll
    for (int k = 0; k < PER; ++k) buf[k] = rowp[k * NT + t];

    // ---- branchless sumsq ----
    float sumsq = 0.0f;
    #pragma unroll
    for (int k = 0; k < PER; ++k) {
        sumsq = fmaf(buf[k].x, buf[k].x, sumsq);
        sumsq = fmaf(buf[k].y, buf[k].y, sumsq);
        sumsq = fmaf(buf[k].z, buf[k].z, sumsq);
        sumsq = fmaf(buf[k].w, buf[k].w, sumsq);
    }
    #pragma unroll
    for (int off = 32; off > 0; off >>= 1)
        sumsq += __shfl_down(sumsq, off, 64);
    if (lane == 0) s_part[t >> 6] = sumsq;
    __syncthreads();
    if (t == 0) {
        float tot = 0.0f;
        #pragma unroll
        for (int i = 0; i < NT / 64; ++i) tot += s_part[i];
        s_scale = 1.0f / sqrtf(fmaxf(tot, 1e-12f));
    }

    // ---- filter: branchless mask -> one reservation atomic -> predicated
    //      writes. Uniform bisection fallback (never fires for N(0,1)). ----
    float T = T0, lo = -3.0e38f, hi = 3.0e38f;
    unsigned cnt = 0;
    for (int attempt = 0; attempt < 25; ++attempt) {
        __syncthreads();
        if (t == 0) s_cnt = 0;
        __syncthreads();

        unsigned msk = 0;
        #pragma unroll
        for (int k = 0; k < PER; ++k) {
            msk |= (buf[k].x > T) ? (1u << (4 * k + 0)) : 0u;
            msk |= (buf[k].y > T) ? (1u << (4 * k + 1)) : 0u;
            msk |= (buf[k].z > T) ? (1u << (4 * k + 2)) : 0u;
            msk |= (buf[k].w > T) ? (1u << (4 * k + 3)) : 0u;
        }
        unsigned base = 0;
        if (msk) base = atomicAdd(&s_cnt, (unsigned)__popc(msk));
        if (msk) {
            #pragma unroll
            for (int k = 0; k < PER; ++k) {
                #pragma unroll
                for (int c = 0; c < 4; ++c) {
                    float v = (c == 0) ? buf[k].x : (c == 1) ? buf[k].y
                            : (c == 2) ? buf[k].z : buf[k].w;
                    if (v > T) {
                        if (base < CAP) {
                            unsigned u  = __float_as_uint(v);
                            unsigned mm = u ^ (((unsigned)((int)u >> 31)) | 0x80000000u);
                            int idx = (k * NT + t) * 4 + c;
                            s_cand[base] = ((unsigned long long)mm << 32) |
                                           (unsigned)(16383 - idx);
                        }
                        base++;
                    }
                }
            }
        }
        __syncthreads();
        cnt = s_cnt;
        if (cnt >= KSEL && cnt <= CAP) break;
        if (cnt < KSEL) { hi = T; T = (lo < -1.0e38f) ? T - 1.0f : 0.5f * (lo + T); }
        else            { lo = T; T = (hi >  1.0e38f) ? T + 1.0f : 0.5f * (T + hi); }
    }
    if (cnt > CAP) cnt = CAP;
    const float scale = s_scale;   // ordered by barriers above

    // ---- repack with normalized fp32-rounded value (rounding ties ->
    //      idx-asc tiebreak in low bits matches jax.lax.top_k) ----
    for (unsigned i = t; i < cnt; i += NT) {
        unsigned long long p = s_cand[i];
        unsigned m = (unsigned)(p >> 32);
        unsigned u = (m & 0x80000000u) ? (m ^ 0x80000000u) : ~m;
        float vn = __uint_as_float(u) * scale;
        unsigned u2 = __float_as_uint(vn);
        unsigned m2 = u2 ^ (((unsigned)((int)u2 >> 31)) | 0x80000000u);
        s_cand[i] = ((unsigned long long)m2 << 32) | (p & 0xFFFFFFFFull);
    }
    __syncthreads();

    // ---- all-pairs rank (ranks unique via idx tiebreak) + write ----
    for (unsigned i = t; i < cnt; i += NT) {
        unsigned long long p = s_cand[i];
        int rank = 0;
        for (unsigned j = 0; j < cnt; ++j) rank += (s_cand[j] > p) ? 1 : 0;
        if (rank < KSEL) {
            unsigned m = (unsigned)(p >> 32);
            unsigned u = (m & 0x80000000u) ? (m ^ 0x80000000u) : ~m;
            float vn = __uint_as_float(u);
            int idx = 16383 - (int)(unsigned)(p & 0xFFFFFFFFull);
            out[row * KSEL + rank] = vn;
            float* coor = out + VALS_TOTAL + ((size_t)row * KSEL + rank) * 2;
            coor[0] = (float)(idx >> 7);          // h = idx / 128
            coor[1] = (float)(idx & (WDIM - 1));  // w = idx % 128
        }
    }
}

extern "C" void kernel_launch(void* const* d_in, const int* in_sizes, int n_in,
                              void* d_out, int out_size, void* d_ws, size_t ws_size,
                              hipStream_t stream) {
    const float* x = (const float*)d_in[0];
    float* out = (float*)d_out;
    topk_rows<<<NROWS, NT, 0, stream>>>(x, out);
}

// Round 5
// 355.212 us; speedup vs baseline: 1.1012x; 1.1012x over previous
//
#include <hip/hip_runtime.h>

// TopK_36653250904599: x [16,256,128,128] f32 -> l2-normalize over HW=16384,
// top-16 values [B,C,16] + (h,w) coords [B,C,16,2] (coords stored as floats;
// harness reads whole tuple buffer as float32).
//
// R5 = R4 with the compile fix: __builtin_nontemporal_load requires a native
// clang vector type, not HIP_vector_type -> load via ext_vector_type(4).
// Structure: R2's memory shape (256 threads x 16 float4/thread, best
// measured) + branchless filter (64-bit candidate mask, ONE exec-masked LDS
// atomicAdd per candidate-holding thread, predicated writes) + nontemporal
// streaming loads + 2 barriers in the common path.
// R3's regression was the forced __launch_bounds__(512,8) (VGPR<=64 ->
// spills), NOT the filter -- do not re-add it.
// Candidate order in s_cand is irrelevant: rank phase orders by (value,idx).

#define KSEL 16
#define HW   16384
#define WDIM 128
#define CAP  1024
#define T0   2.5f
#define NROWS 4096
#define NT   256
#define PER  16                     // float4 per thread
#define VALS_TOTAL (NROWS * KSEL)   // 65536 value floats, then coords

typedef float floatx4 __attribute__((ext_vector_type(4)));

__global__ __launch_bounds__(NT) void topk_rows(const float* __restrict__ x,
                                                float* __restrict__ out) {
    const int row  = blockIdx.x;
    const int t    = threadIdx.x;
    const int lane = t & 63;

    __shared__ unsigned long long s_cand[CAP];
    __shared__ unsigned s_cnt;
    __shared__ float s_part[NT / 64];
    __shared__ float s_scale;

    const floatx4* rowp = (const floatx4*)(x + (size_t)row * HW);

    // ---- one unbroken batch of 16 independent nontemporal 16B loads ----
    floatx4 buf[PER];
    #pragma unroll
    for (int k = 0; k < PER; ++k)
        buf[k] = __builtin_nontemporal_load(&rowp[k * NT + t]);

    // ---- branchless sumsq + wave/block reduce ----
    float sumsq = 0.0f;
    #pragma unroll
    for (int k = 0; k < PER; ++k) {
        sumsq = fmaf(buf[k].x, buf[k].x, sumsq);
        sumsq = fmaf(buf[k].y, buf[k].y, sumsq);
        sumsq = fmaf(buf[k].z, buf[k].z, sumsq);
        sumsq = fmaf(buf[k].w, buf[k].w, sumsq);
    }
    #pragma unroll
    for (int off = 32; off > 0; off >>= 1)
        sumsq += __shfl_down(sumsq, off, 64);
    if (lane == 0) s_part[t >> 6] = sumsq;
    if (t == 0) s_cnt = 0;
    __syncthreads();                      // partials + s_cnt=0 visible
    if (t == 0) {
        float tot = 0.0f;
        #pragma unroll
        for (int i = 0; i < NT / 64; ++i) tot += s_part[i];
        s_scale = 1.0f / sqrtf(fmaxf(tot, 1e-12f));
    }

    // ---- attempt 0: branchless mask -> one reservation atomic ->
    //      predicated writes ----
    float T = T0;
    unsigned long long msk = 0;
    #pragma unroll
    for (int k = 0; k < PER; ++k) {
        msk |= (buf[k].x > T) ? (1ull << (4 * k + 0)) : 0ull;
        msk |= (buf[k].y > T) ? (1ull << (4 * k + 1)) : 0ull;
        msk |= (buf[k].z > T) ? (1ull << (4 * k + 2)) : 0ull;
        msk |= (buf[k].w > T) ? (1ull << (4 * k + 3)) : 0ull;
    }
    unsigned base = 0;
    if (msk) base = atomicAdd(&s_cnt, (unsigned)__popcll(msk));
    if (msk) {
        #pragma unroll
        for (int k = 0; k < PER; ++k) {
            #pragma unroll
            for (int c = 0; c < 4; ++c) {
                float v = (c == 0) ? buf[k].x : (c == 1) ? buf[k].y
                        : (c == 2) ? buf[k].z : buf[k].w;
                if (v > T) {
                    if (base < CAP) {
                        unsigned u  = __float_as_uint(v);
                        unsigned mm = u ^ (((unsigned)((int)u >> 31)) | 0x80000000u);
                        int idx = (k * NT + t) * 4 + c;
                        s_cand[base] = ((unsigned long long)mm << 32) |
                                       (unsigned)(16383 - idx);
                    }
                    base++;
                }
            }
        }
    }
    __syncthreads();                      // writes + s_scale visible
    unsigned cnt = s_cnt;

    // ---- uniform bisection fallback (never fires for N(0,1) rows) ----
    if (cnt < KSEL || cnt > CAP) {
        float lo = -3.0e38f, hi = 3.0e38f;
        for (int attempt = 0; attempt < 24 && (cnt < KSEL || cnt > CAP); ++attempt) {
            if (cnt < KSEL) { hi = T; T = (lo < -1.0e38f) ? T - 1.0f : 0.5f * (lo + T); }
            else            { lo = T; T = (hi >  1.0e38f) ? T + 1.0f : 0.5f * (T + hi); }
            __syncthreads();
            if (t == 0) s_cnt = 0;
            __syncthreads();
            msk = 0;
            #pragma unroll
            for (int k = 0; k < PER; ++k) {
                msk |= (buf[k].x > T) ? (1ull << (4 * k + 0)) : 0ull;
                msk |= (buf[k].y > T) ? (1ull << (4 * k + 1)) : 0ull;
                msk |= (buf[k].z > T) ? (1ull << (4 * k + 2)) : 0ull;
                msk |= (buf[k].w > T) ? (1ull << (4 * k + 3)) : 0ull;
            }
            base = 0;
            if (msk) base = atomicAdd(&s_cnt, (unsigned)__popcll(msk));
            if (msk) {
                #pragma unroll
                for (int k = 0; k < PER; ++k) {
                    #pragma unroll
                    for (int c = 0; c < 4; ++c) {
                        float v = (c == 0) ? buf[k].x : (c == 1) ? buf[k].y
                                : (c == 2) ? buf[k].z : buf[k].w;
                        if (v > T) {
                            if (base < CAP) {
                                unsigned u  = __float_as_uint(v);
                                unsigned mm = u ^ (((unsigned)((int)u >> 31)) | 0x80000000u);
                                int idx = (k * NT + t) * 4 + c;
                                s_cand[base] = ((unsigned long long)mm << 32) |
                                               (unsigned)(16383 - idx);
                            }
                            base++;
                        }
                    }
                }
            }
            __syncthreads();
            cnt = s_cnt;
        }
        if (cnt > CAP) cnt = CAP;
    }
    const float scale = s_scale;

    // ---- repack with normalized fp32-rounded value (rounding ties ->
    //      idx-asc tiebreak in low bits matches jax.lax.top_k) ----
    for (unsigned i = t; i < cnt; i += NT) {
        unsigned long long p = s_cand[i];
        unsigned m = (unsigned)(p >> 32);
        unsigned u = (m & 0x80000000u) ? (m ^ 0x80000000u) : ~m;
        float vn = __uint_as_float(u) * scale;
        unsigned u2 = __float_as_uint(vn);
        unsigned m2 = u2 ^ (((unsigned)((int)u2 >> 31)) | 0x80000000u);
        s_cand[i] = ((unsigned long long)m2 << 32) | (p & 0xFFFFFFFFull);
    }
    __syncthreads();

    // ---- all-pairs rank (ranks unique via idx tiebreak) + write ----
    for (unsigned i = t; i < cnt; i += NT) {
        unsigned long long p = s_cand[i];
        int rank = 0;
        for (unsigned j = 0; j < cnt; ++j) rank += (s_cand[j] > p) ? 1 : 0;
        if (rank < KSEL) {
            unsigned m = (unsigned)(p >> 32);
            unsigned u = (m & 0x80000000u) ? (m ^ 0x80000000u) : ~m;
            float vn = __uint_as_float(u);
            int idx = 16383 - (int)(unsigned)(p & 0xFFFFFFFFull);
            out[row * KSEL + rank] = vn;
            float* coor = out + VALS_TOTAL + ((size_t)row * KSEL + rank) * 2;
            coor[0] = (float)(idx >> 7);          // h = idx / 128
            coor[1] = (float)(idx & (WDIM - 1));  // w = idx % 128
        }
    }
}

extern "C" void kernel_launch(void* const* d_in, const int* in_sizes, int n_in,
                              void* d_out, int out_size, void* d_ws, size_t ws_size,
                              hipStream_t stream) {
    const float* x = (const float*)d_in[0];
    float* out = (float*)d_out;
    topk_rows<<<NROWS, NT, 0, stream>>>(x, out);
}

// Round 6
// 337.760 us; speedup vs baseline: 1.1581x; 1.0517x over previous
//
#include <hip/hip_runtime.h>

// TopK_36653250904599: x [16,256,128,128] f32 -> l2-normalize over HW=16384,
// top-16 values [B,C,16] + (h,w) coords [B,C,16,2] (coords stored as floats).
//
// R6: two-kernel split. K1 = pure streaming (quarter-row blocks, tiny LDS,
// high occupancy, no selection tail) -> ws {qsum, qcnt, compacted cands>T0}.
// K2 = per-row selection (gather ~102 cands, scale, repack with normalized
// fp32-rounded values, all-pairs rank). Fallback (cnt outside [16,1024] or
// quarter overflow -- never fires for N(0,1)) re-reads the row in K2 with
// threshold bisection. R5's single-kernel shape plateaued at ~2.4 TB/s:
// barrier-coupled block tails throttle streaming.

#define KSEL 16
#define HW   16384
#define QSZ  4096                   // quarter-row elements
#define WDIM 128
#define CAP  1024
#define CAPQ 256
#define T0   2.5f
#define NROWS 4096
#define NQ   (NROWS * 4)            // 16384 quarter blocks
#define VALS_TOTAL (NROWS * KSEL)   // 65536 value floats, then coords

typedef float floatx4 __attribute__((ext_vector_type(4)));

// ws layout (bytes):
//   qsum : float[NQ]                @ 0        (64 KB)
//   qcnt : uint[NQ]                 @ 64 KB    (64 KB)
//   qcand: ull[NQ * CAPQ]           @ 128 KB   (32 MB)

__global__ __launch_bounds__(256) void k1_stream(const float* __restrict__ x,
                                                 float* __restrict__ qsum,
                                                 unsigned* __restrict__ qcnt,
                                                 unsigned long long* __restrict__ qcand) {
    const int b    = blockIdx.x;          // quarter id
    const int row  = b >> 2;
    const int q    = b & 3;
    const int t    = threadIdx.x;
    const int lane = t & 63;

    __shared__ unsigned long long s_cand[CAPQ];
    __shared__ unsigned s_cnt;
    __shared__ float s_part[4];

    if (t == 0) s_cnt = 0;
    __syncthreads();

    const floatx4* p = (const floatx4*)(x + (size_t)row * HW + q * QSZ);

    floatx4 buf[4];
    #pragma unroll
    for (int k = 0; k < 4; ++k)
        buf[k] = __builtin_nontemporal_load(&p[k * 256 + t]);

    float sumsq = 0.0f;
    #pragma unroll
    for (int k = 0; k < 4; ++k) {
        sumsq = fmaf(buf[k].x, buf[k].x, sumsq);
        sumsq = fmaf(buf[k].y, buf[k].y, sumsq);
        sumsq = fmaf(buf[k].z, buf[k].z, sumsq);
        sumsq = fmaf(buf[k].w, buf[k].w, sumsq);
    }

    // branchless 16-bit candidate mask, one reservation atomic, predicated pushes
    unsigned msk = 0;
    #pragma unroll
    for (int k = 0; k < 4; ++k) {
        msk |= (buf[k].x > T0) ? (1u << (4 * k + 0)) : 0u;
        msk |= (buf[k].y > T0) ? (1u << (4 * k + 1)) : 0u;
        msk |= (buf[k].z > T0) ? (1u << (4 * k + 2)) : 0u;
        msk |= (buf[k].w > T0) ? (1u << (4 * k + 3)) : 0u;
    }
    unsigned base = 0;
    if (msk) base = atomicAdd(&s_cnt, (unsigned)__popc(msk));
    if (msk) {
        #pragma unroll
        for (int k = 0; k < 4; ++k) {
            #pragma unroll
            for (int c = 0; c < 4; ++c) {
                float v = (c == 0) ? buf[k].x : (c == 1) ? buf[k].y
                        : (c == 2) ? buf[k].z : buf[k].w;
                if (v > T0) {
                    if (base < CAPQ) {
                        unsigned u  = __float_as_uint(v);
                        unsigned mm = u ^ (((unsigned)((int)u >> 31)) | 0x80000000u);
                        int idx = q * QSZ + (k * 256 + t) * 4 + c;  // in-row idx
                        s_cand[base] = ((unsigned long long)mm << 32) |
                                       (unsigned)(16383 - idx);
                    }
                    base++;
                }
            }
        }
    }

    #pragma unroll
    for (int off = 32; off > 0; off >>= 1)
        sumsq += __shfl_down(sumsq, off, 64);
    if (lane == 0) s_part[t >> 6] = sumsq;
    __syncthreads();

    unsigned cnt = s_cnt;
    unsigned wr = cnt < CAPQ ? cnt : CAPQ;
    for (unsigned i = t; i < wr; i += 256)
        qcand[(size_t)b * CAPQ + i] = s_cand[i];
    if (t == 0) {
        qcnt[b] = cnt;  // true count (overflow detected in K2)
        qsum[b] = s_part[0] + s_part[1] + s_part[2] + s_part[3];
    }
}

__global__ __launch_bounds__(256) void k2_select(const float* __restrict__ x,
                                                 const float* __restrict__ qsum,
                                                 const unsigned* __restrict__ qcnt,
                                                 const unsigned long long* __restrict__ qcand,
                                                 float* __restrict__ out) {
    const int row = blockIdx.x;
    const int t   = threadIdx.x;

    __shared__ unsigned long long s_cand[CAP];
    __shared__ unsigned s_qc[4];
    __shared__ float s_qs[4];
    __shared__ unsigned s_cnt;
    __shared__ float s_scale;

    if (t < 4) {
        s_qc[t] = qcnt[row * 4 + t];
        s_qs[t] = qsum[row * 4 + t];
    }
    __syncthreads();

    const unsigned c0 = s_qc[0], c1 = s_qc[1], c2 = s_qc[2], c3 = s_qc[3];
    if (t == 0)
        s_scale = 1.0f / sqrtf(fmaxf(s_qs[0] + s_qs[1] + s_qs[2] + s_qs[3], 1e-12f));
    const bool ovf = (c0 > CAPQ) | (c1 > CAPQ) | (c2 > CAPQ) | (c3 > CAPQ);
    const unsigned tot = c0 + c1 + c2 + c3;

    unsigned cnt;
    if (!ovf && tot >= KSEL && tot <= CAP) {
        // fast path: gather the 4 compacted quarter lists
        const unsigned off[4] = {0u, c0, c0 + c1, c0 + c1 + c2};
        const unsigned cc[4]  = {c0, c1, c2, c3};
        #pragma unroll
        for (int q = 0; q < 4; ++q)
            for (unsigned i = t; i < cc[q]; i += 256)
                s_cand[off[q] + i] = qcand[(size_t)(row * 4 + q) * CAPQ + i];
        cnt = tot;
        __syncthreads();            // gather + s_scale visible
    } else {
        // slow path (never for N(0,1)): bisect T, re-reading the row
        const float* xr = x + (size_t)row * HW;
        float T = T0, lo = -3.0e38f, hi = 3.0e38f;
        cnt = 0;
        for (int it = 0; it < 32; ++it) {
            __syncthreads();
            if (t == 0) s_cnt = 0;
            __syncthreads();
            for (int i = t; i < HW; i += 256) {
                float v = xr[i];
                if (v > T) {
                    unsigned slot = atomicAdd(&s_cnt, 1u);
                    if (slot < CAP) {
                        unsigned u  = __float_as_uint(v);
                        unsigned mm = u ^ (((unsigned)((int)u >> 31)) | 0x80000000u);
                        s_cand[slot] = ((unsigned long long)mm << 32) |
                                       (unsigned)(16383 - i);
                    }
                }
            }
            __syncthreads();
            cnt = s_cnt;
            if (cnt >= KSEL && cnt <= CAP) break;
            if (cnt < KSEL) { hi = T; T = (lo < -1.0e38f) ? T - 1.0f : 0.5f * (lo + T); }
            else            { lo = T; T = (hi >  1.0e38f) ? T + 1.0f : 0.5f * (T + hi); }
        }
        if (cnt > CAP) cnt = CAP;
    }
    const float scale = s_scale;    // ordered by barriers in both paths

    // repack with normalized fp32-rounded value (rounding ties -> idx-asc
    // tiebreak in low bits matches jax.lax.top_k)
    for (unsigned i = t; i < cnt; i += 256) {
        unsigned long long p = s_cand[i];
        unsigned m = (unsigned)(p >> 32);
        unsigned u = (m & 0x80000000u) ? (m ^ 0x80000000u) : ~m;
        float vn = __uint_as_float(u) * scale;
        unsigned u2 = __float_as_uint(vn);
        unsigned m2 = u2 ^ (((unsigned)((int)u2 >> 31)) | 0x80000000u);
        s_cand[i] = ((unsigned long long)m2 << 32) | (p & 0xFFFFFFFFull);
    }
    __syncthreads();

    // all-pairs rank (ranks unique via idx tiebreak) + write
    for (unsigned i = t; i < cnt; i += 256) {
        unsigned long long p = s_cand[i];
        int rank = 0;
        for (unsigned j = 0; j < cnt; ++j) rank += (s_cand[j] > p) ? 1 : 0;
        if (rank < KSEL) {
            unsigned m = (unsigned)(p >> 32);
            unsigned u = (m & 0x80000000u) ? (m ^ 0x80000000u) : ~m;
            float vn = __uint_as_float(u);
            int idx = 16383 - (int)(unsigned)(p & 0xFFFFFFFFull);
            out[row * KSEL + rank] = vn;
            float* coor = out + VALS_TOTAL + ((size_t)row * KSEL + rank) * 2;
            coor[0] = (float)(idx >> 7);          // h
            coor[1] = (float)(idx & (WDIM - 1));  // w
        }
    }
}

extern "C" void kernel_launch(void* const* d_in, const int* in_sizes, int n_in,
                              void* d_out, int out_size, void* d_ws, size_t ws_size,
                              hipStream_t stream) {
    const float* x = (const float*)d_in[0];
    float* out = (float*)d_out;
    char* ws = (char*)d_ws;
    float* qsum = (float*)ws;                                   // 64 KB
    unsigned* qcnt = (unsigned*)(ws + 64 * 1024);               // 64 KB
    unsigned long long* qcand =
        (unsigned long long*)(ws + 128 * 1024);                 // 32 MB

    k1_stream<<<NQ, 256, 0, stream>>>(x, qsum, qcnt, qcand);
    k2_select<<<NROWS, 256, 0, stream>>>(x, qsum, qcnt, qcand, out);
}